// Round 1
// baseline (310.691 us; speedup 1.0000x reference)
//
#include <hip/hip_runtime.h>
#include <math.h>

#define B_ 2
#define T_ 4096
#define D_ 128
#define H_ 128
#define CHUNK 128
#define NCB (T_/CHUNK)       // 32 chunks per batch
#define NCHUNKS (B_*NCB)     // 64 chunks total
#define NTOK (B_*T_)         // 8192 tokens
#define LN_EPS 1e-5f
#define EPS_ATTN 1e-6f
#define BM 32

// ---------------- LayerNorm (used for LN1 and LN2) ----------------
__global__ __launch_bounds__(128) void k_ln(const float* __restrict__ in,
    const float* __restrict__ g, const float* __restrict__ b,
    float* __restrict__ out) {
  const int tok = blockIdx.x;
  const int j = threadIdx.x;
  float v = in[tok*D_ + j];
  float s = v, q = v*v;
  #pragma unroll
  for (int off = 32; off > 0; off >>= 1) {
    s += __shfl_down(s, off);
    q += __shfl_down(q, off);
  }
  __shared__ float ss[2], qq[2];
  if ((j & 63) == 0) { ss[j>>6] = s; qq[j>>6] = q; }
  __syncthreads();
  const float mean = (ss[0]+ss[1]) * (1.0f/D_);
  const float var  = (qq[0]+qq[1]) * (1.0f/D_) - mean*mean;
  const float r = rsqrtf(var + LN_EPS);
  out[tok*D_ + j] = (v - mean) * r * g[j] + b[j];
}

// ---------------- Fused QKVG projections ----------------
// Qp = phi(x@Wq), Kp = phi(x@Wk), Vg = (x@Wv)*sigmoid(x@Wg+bg)
// phi(x) = elu(x)+1 = x>0 ? x+1 : exp(x)
__global__ __launch_bounds__(128) void k_qkvg(const float* __restrict__ x,
    const float* __restrict__ Wq, const float* __restrict__ Wk,
    const float* __restrict__ Wv, const float* __restrict__ Wg,
    const float* __restrict__ bg,
    float* __restrict__ Qp, float* __restrict__ Kp, float* __restrict__ Vg) {
  const int j = threadIdx.x;           // output column 0..127
  const int m0 = blockIdx.x * BM;      // token tile base
  __shared__ float xsT[D_][BM+4];      // [k][m], padded row (144B, 16B aligned)
  #pragma unroll 4
  for (int m = 0; m < BM; ++m) xsT[j][m] = x[(m0+m)*D_ + j];
  __syncthreads();
  // pass 1: Q and K together
  {
    float accq[BM], acck[BM];
    #pragma unroll
    for (int m = 0; m < BM; ++m) { accq[m] = 0.f; acck[m] = 0.f; }
    for (int k = 0; k < D_; ++k) {
      const float wq = Wq[k*H_ + j];
      const float wk = Wk[k*H_ + j];
      const float4* xr = (const float4*)(&xsT[k][0]);
      #pragma unroll
      for (int m4 = 0; m4 < BM/4; ++m4) {
        const float4 xv = xr[m4];
        accq[4*m4+0] += xv.x*wq; accq[4*m4+1] += xv.y*wq;
        accq[4*m4+2] += xv.z*wq; accq[4*m4+3] += xv.w*wq;
        acck[4*m4+0] += xv.x*wk; acck[4*m4+1] += xv.y*wk;
        acck[4*m4+2] += xv.z*wk; acck[4*m4+3] += xv.w*wk;
      }
    }
    #pragma unroll
    for (int m = 0; m < BM; ++m) {
      const float qv = accq[m];
      const float kv = acck[m];
      Qp[(m0+m)*H_ + j] = (qv > 0.f) ? (qv + 1.f) : expf(qv);
      Kp[(m0+m)*H_ + j] = (kv > 0.f) ? (kv + 1.f) : expf(kv);
    }
  }
  // pass 2: V and G together, fuse gate
  {
    float accv[BM], accg[BM];
    #pragma unroll
    for (int m = 0; m < BM; ++m) { accv[m] = 0.f; accg[m] = 0.f; }
    for (int k = 0; k < D_; ++k) {
      const float wv = Wv[k*D_ + j];
      const float wg = Wg[k*D_ + j];
      const float4* xr = (const float4*)(&xsT[k][0]);
      #pragma unroll
      for (int m4 = 0; m4 < BM/4; ++m4) {
        const float4 xv = xr[m4];
        accv[4*m4+0] += xv.x*wv; accv[4*m4+1] += xv.y*wv;
        accv[4*m4+2] += xv.z*wv; accv[4*m4+3] += xv.w*wv;
        accg[4*m4+0] += xv.x*wg; accg[4*m4+1] += xv.y*wg;
        accg[4*m4+2] += xv.z*wg; accg[4*m4+3] += xv.w*wg;
      }
    }
    const float bgj = bg[j];
    #pragma unroll
    for (int m = 0; m < BM; ++m) {
      const float gv = 1.f / (1.f + expf(-(accg[m] + bgj)));
      Vg[(m0+m)*D_ + j] = accv[m] * gv;
    }
  }
}

// ---------------- Per-chunk KV = Kp_c^T @ Vg_c and Ksum_c ----------------
__global__ __launch_bounds__(256) void k_chunkkv(const float* __restrict__ Kp,
    const float* __restrict__ Vg, float* __restrict__ KV,
    float* __restrict__ Ksum) {
  const int c = blockIdx.x;
  const int tid = threadIdx.x;
  const int hq = tid >> 4, dq = tid & 15;
  const int base = c * CHUNK;
  __shared__ float ks[32][D_+4];
  __shared__ float vs[32][D_+4];
  float acc[8][8];
  #pragma unroll
  for (int i = 0; i < 8; ++i)
    #pragma unroll
    for (int j2 = 0; j2 < 8; ++j2) acc[i][j2] = 0.f;
  for (int t0 = 0; t0 < CHUNK; t0 += 32) {
    for (int i = tid; i < 32*D_; i += 256) {
      const int tt = i >> 7, kk = i & 127;
      ks[tt][kk] = Kp[(base+t0+tt)*H_ + kk];
      vs[tt][kk] = Vg[(base+t0+tt)*D_ + kk];
    }
    __syncthreads();
    for (int t = 0; t < 32; ++t) {
      float kh[8], vd[8];
      *(float4*)&kh[0] = *(const float4*)&ks[t][hq*8];
      *(float4*)&kh[4] = *(const float4*)&ks[t][hq*8+4];
      *(float4*)&vd[0] = *(const float4*)&vs[t][dq*8];
      *(float4*)&vd[4] = *(const float4*)&vs[t][dq*8+4];
      #pragma unroll
      for (int i = 0; i < 8; ++i)
        #pragma unroll
        for (int j2 = 0; j2 < 8; ++j2) acc[i][j2] += kh[i]*vd[j2];
    }
    __syncthreads();
  }
  float* outp = KV + (size_t)c*(H_*D_);
  #pragma unroll
  for (int i = 0; i < 8; ++i) {
    const int h = hq*8+i;
    *(float4*)&outp[h*D_ + dq*8]   = make_float4(acc[i][0],acc[i][1],acc[i][2],acc[i][3]);
    *(float4*)&outp[h*D_ + dq*8+4] = make_float4(acc[i][4],acc[i][5],acc[i][6],acc[i][7]);
  }
  if (tid < H_) {
    float s = 0.f;
    for (int t = 0; t < CHUNK; ++t) s += Kp[(base+t)*H_ + tid];
    Ksum[c*H_ + tid] = s;
  }
}

// ---------------- Exclusive prefix over chunks (in place) ----------------
__global__ __launch_bounds__(256) void k_prefix(float* __restrict__ KV,
    float* __restrict__ Ksum) {
  if (blockIdx.x < 128) {
    const int gid = blockIdx.x*256 + threadIdx.x;   // 0..32767
    const int b = gid >> 14;                        // batch
    const int e = gid & 16383;                      // element in 128x128
    float run = 0.f;
    for (int cc = 0; cc < NCB; ++cc) {
      const size_t idx = (size_t)(b*NCB + cc)*(H_*D_) + e;
      const float v = KV[idx]; KV[idx] = run; run += v;
    }
  } else {
    const int t = threadIdx.x;                      // 0..255 = B_*H_
    const int b = t >> 7, h = t & 127;
    float run = 0.f;
    for (int cc = 0; cc < NCB; ++cc) {
      const int idx = (b*NCB + cc)*H_ + h;
      const float v = Ksum[idx]; Ksum[idx] = run; run += v;
    }
  }
}

// ---------------- Masked intra-chunk scores A and rowsums ----------------
__global__ __launch_bounds__(256) void k_scores(const float* __restrict__ Qp,
    const float* __restrict__ Kp, float* __restrict__ A,
    float* __restrict__ rowsum) {
  const int c = blockIdx.x, tid = threadIdx.x;
  const int ty = tid >> 4, tx = tid & 15;
  const int base = c * CHUNK;
  __shared__ float qT[32][CHUNK+4];
  __shared__ float kT[32][CHUNK+4];
  __shared__ float rbuf[CHUNK][17];
  float acc[8][8];
  #pragma unroll
  for (int i = 0; i < 8; ++i)
    #pragma unroll
    for (int j2 = 0; j2 < 8; ++j2) acc[i][j2] = 0.f;
  for (int k0 = 0; k0 < H_; k0 += 32) {
    for (int i = tid; i < 32*CHUNK; i += 256) {
      const int kk = i & 31, t = i >> 5;
      qT[kk][t] = Qp[(base+t)*H_ + k0 + kk];
      kT[kk][t] = Kp[(base+t)*H_ + k0 + kk];
    }
    __syncthreads();
    for (int k = 0; k < 32; ++k) {
      float av[8], bv[8];
      *(float4*)&av[0] = *(const float4*)&qT[k][ty*8];
      *(float4*)&av[4] = *(const float4*)&qT[k][ty*8+4];
      *(float4*)&bv[0] = *(const float4*)&kT[k][tx*8];
      *(float4*)&bv[4] = *(const float4*)&kT[k][tx*8+4];
      #pragma unroll
      for (int i = 0; i < 8; ++i)
        #pragma unroll
        for (int j2 = 0; j2 < 8; ++j2) acc[i][j2] += av[i]*bv[j2];
    }
    __syncthreads();
  }
  // causal mask (keep s<=t), per-row partial sums
  float rs[8];
  #pragma unroll
  for (int i = 0; i < 8; ++i) {
    const int t = ty*8+i;
    rs[i] = 0.f;
    #pragma unroll
    for (int j2 = 0; j2 < 8; ++j2) {
      const int s2 = tx*8+j2;
      if (s2 > t) acc[i][j2] = 0.f;
      rs[i] += acc[i][j2];
    }
  }
  float* Ac = A + (size_t)c*(CHUNK*CHUNK);
  #pragma unroll
  for (int i = 0; i < 8; ++i) {
    const int t = ty*8+i;
    *(float4*)&Ac[t*CHUNK + tx*8]   = make_float4(acc[i][0],acc[i][1],acc[i][2],acc[i][3]);
    *(float4*)&Ac[t*CHUNK + tx*8+4] = make_float4(acc[i][4],acc[i][5],acc[i][6],acc[i][7]);
  }
  #pragma unroll
  for (int i = 0; i < 8; ++i) rbuf[ty*8+i][tx] = rs[i];
  __syncthreads();
  if (tid < CHUNK) {
    float s = 0.f;
    #pragma unroll
    for (int x2 = 0; x2 < 16; ++x2) s += rbuf[tid][x2];
    rowsum[c*CHUNK + tid] = s;
  }
}

// ---------------- numerator = [A|Qp]@[Vg;Sprev], denom, attn ----------------
__global__ __launch_bounds__(256) void k_attnout(const float* __restrict__ A,
    const float* __restrict__ Vg, const float* __restrict__ Qp,
    const float* __restrict__ KV, const float* __restrict__ Ksum,
    const float* __restrict__ rowsum, float* __restrict__ attn) {
  const int c = blockIdx.x, tid = threadIdx.x;
  const int ty = tid >> 4, tx = tid & 15;
  const int base = c * CHUNK;
  __shared__ float aT[32][CHUNK+4];   // [k][t]
  __shared__ float bs[32][D_+4];      // [k][d]
  __shared__ float kss[32];
  float acc[8][8];
  float dsum[8];
  #pragma unroll
  for (int i = 0; i < 8; ++i) {
    dsum[i] = 0.f;
    #pragma unroll
    for (int j2 = 0; j2 < 8; ++j2) acc[i][j2] = 0.f;
  }
  const float* Ac  = A  + (size_t)c*(CHUNK*CHUNK);
  const float* KVc = KV + (size_t)c*(H_*D_);
  for (int k0 = 0; k0 < CHUNK + H_; k0 += 32) {
    for (int i = tid; i < 32*CHUNK; i += 256) {
      const int kk = i & 31, t = i >> 5;
      const int k = k0 + kk;
      aT[kk][t] = (k < CHUNK) ? Ac[t*CHUNK + k] : Qp[(base+t)*H_ + (k-CHUNK)];
    }
    for (int i = tid; i < 32*D_; i += 256) {
      const int kk = i >> 7, d = i & 127;
      const int k = k0 + kk;
      bs[kk][d] = (k < CHUNK) ? Vg[(base+k)*D_ + d] : KVc[(k-CHUNK)*D_ + d];
    }
    if (tid < 32) {
      const int k = k0 + tid;
      kss[tid] = (k >= CHUNK) ? Ksum[c*H_ + (k-CHUNK)] : 0.f;
    }
    __syncthreads();
    for (int k = 0; k < 32; ++k) {
      float av[8], bv[8];
      *(float4*)&av[0] = *(const float4*)&aT[k][ty*8];
      *(float4*)&av[4] = *(const float4*)&aT[k][ty*8+4];
      *(float4*)&bv[0] = *(const float4*)&bs[k][tx*8];
      *(float4*)&bv[4] = *(const float4*)&bs[k][tx*8+4];
      const float ksv = kss[k];
      #pragma unroll
      for (int i = 0; i < 8; ++i) {
        dsum[i] += av[i]*ksv;
        #pragma unroll
        for (int j2 = 0; j2 < 8; ++j2) acc[i][j2] += av[i]*bv[j2];
      }
    }
    __syncthreads();
  }
  #pragma unroll
  for (int i = 0; i < 8; ++i) {
    const int t = ty*8+i;
    const float den = fmaxf(rowsum[c*CHUNK + t] + dsum[i], EPS_ATTN);
    const float inv = 1.f/den;
    float* dst = attn + (size_t)(base+t)*D_ + tx*8;
    *(float4*)&dst[0] = make_float4(acc[i][0]*inv, acc[i][1]*inv, acc[i][2]*inv, acc[i][3]*inv);
    *(float4*)&dst[4] = make_float4(acc[i][4]*inv, acc[i][5]*inv, acc[i][6]*inv, acc[i][7]*inv);
  }
}

// ---------------- out_pre = tokens + 0.1*(attn@Wo) ----------------
__global__ __launch_bounds__(128) void k_outproj(const float* __restrict__ attn,
    const float* __restrict__ Wo, const float* __restrict__ tokens,
    float* __restrict__ pre) {
  const int j = threadIdx.x;
  const int m0 = blockIdx.x * BM;
  __shared__ float asT[D_][BM+4];
  #pragma unroll 4
  for (int m = 0; m < BM; ++m) asT[j][m] = attn[(m0+m)*D_ + j];
  __syncthreads();
  float acc[BM];
  #pragma unroll
  for (int m = 0; m < BM; ++m) acc[m] = 0.f;
  for (int k = 0; k < D_; ++k) {
    const float w = Wo[k*D_ + j];
    const float4* ar = (const float4*)(&asT[k][0]);
    #pragma unroll
    for (int m4 = 0; m4 < BM/4; ++m4) {
      const float4 av = ar[m4];
      acc[4*m4+0] += av.x*w; acc[4*m4+1] += av.y*w;
      acc[4*m4+2] += av.z*w; acc[4*m4+3] += av.w*w;
    }
  }
  #pragma unroll
  for (int m = 0; m < BM; ++m)
    pre[(m0+m)*D_ + j] = tokens[(m0+m)*D_ + j] + acc[m]*0.1f;
}

extern "C" void kernel_launch(void* const* d_in, const int* in_sizes, int n_in,
                              void* d_out, int out_size, void* d_ws, size_t ws_size,
                              hipStream_t stream) {
  const float* tokens = (const float*)d_in[0];
  const float* Wq = (const float*)d_in[1];
  const float* Wk = (const float*)d_in[2];
  const float* Wv = (const float*)d_in[3];
  const float* Wg = (const float*)d_in[4];
  const float* bg = (const float*)d_in[5];
  const float* Wo = (const float*)d_in[6];
  const float* g1 = (const float*)d_in[7];
  const float* b1 = (const float*)d_in[8];
  const float* g2 = (const float*)d_in[9];
  const float* b2 = (const float*)d_in[10];

  float* ws = (float*)d_ws;
  const size_t M1 = 1048576;           // floats per (8192,128) buffer
  float* x      = ws;                  // reused as 'pre' after k_outproj
  float* Qp     = ws + 1*M1;
  float* Kp     = ws + 2*M1;
  float* Vg     = ws + 3*M1;
  float* KV     = ws + 4*M1;           // 64 * 128*128
  float* A      = ws + 5*M1;           // 64 * 128*128
  float* attn   = ws + 6*M1;
  float* Ksum   = ws + 7*M1;           // 64*128
  float* rowsum = ws + 7*M1 + 8192;    // 64*128

  k_ln<<<NTOK, 128, 0, stream>>>(tokens, g1, b1, x);
  k_qkvg<<<NTOK/BM, 128, 0, stream>>>(x, Wq, Wk, Wv, Wg, bg, Qp, Kp, Vg);
  k_chunkkv<<<NCHUNKS, 256, 0, stream>>>(Kp, Vg, KV, Ksum);
  k_prefix<<<129, 256, 0, stream>>>(KV, Ksum);
  k_scores<<<NCHUNKS, 256, 0, stream>>>(Qp, Kp, A, rowsum);
  k_attnout<<<NCHUNKS, 256, 0, stream>>>(A, Vg, Qp, KV, Ksum, rowsum, attn);
  k_outproj<<<NTOK/BM, 128, 0, stream>>>(attn, Wo, tokens, x);
  k_ln<<<NTOK, 128, 0, stream>>>(x, g2, b2, (float*)d_out);
}

// Round 2
// 197.542 us; speedup vs baseline: 1.5728x; 1.5728x over previous
//
#include <hip/hip_runtime.h>
#include <math.h>

#define B_ 2
#define T_ 4096
#define D_ 128
#define H_ 128
#define CHUNK 64
#define NCB (T_/CHUNK)       // 64 chunks per batch
#define NCHUNKS (B_*NCB)     // 128 chunks total
#define NTOK (B_*T_)         // 8192 tokens
#define LN_EPS 1e-5f
#define EPS_ATTN 1e-6f

// ---------------- LayerNorm 1 ----------------
__global__ __launch_bounds__(128) void k_ln(const float* __restrict__ in,
    const float* __restrict__ g, const float* __restrict__ b,
    float* __restrict__ out) {
  const int tok = blockIdx.x;
  const int j = threadIdx.x;
  float v = in[tok*D_ + j];
  float s = v, q = v*v;
  #pragma unroll
  for (int off = 32; off > 0; off >>= 1) {
    s += __shfl_down(s, off);
    q += __shfl_down(q, off);
  }
  __shared__ float ss[2], qq[2];
  if ((j & 63) == 0) { ss[j>>6] = s; qq[j>>6] = q; }
  __syncthreads();
  const float mean = (ss[0]+ss[1]) * (1.0f/D_);
  const float var  = (qq[0]+qq[1]) * (1.0f/D_) - mean*mean;
  const float r = rsqrtf(var + LN_EPS);
  out[tok*D_ + j] = (v - mean) * r * g[j] + b[j];
}

// ---------------- Fused QKVG projections, v2 ----------------
// grid (128 token tiles, 2 col halves, 2 pairs), 256 threads.
// pair 0: Qp=phi(x@Wq), Kp=phi(x@Wk).  pair 1: Vg=(x@Wv)*sigmoid(x@Wg+bg).
__global__ __launch_bounds__(256) void k_qkvg2(const float* __restrict__ x,
    const float* __restrict__ Wq, const float* __restrict__ Wk,
    const float* __restrict__ Wv, const float* __restrict__ Wg,
    const float* __restrict__ bg,
    float* __restrict__ Qp, float* __restrict__ Kp, float* __restrict__ Vg) {
  const int tid = threadIdx.x;
  const int m0 = blockIdx.x * 64;
  const int c0 = blockIdx.y * 64;
  const int pair = blockIdx.z;
  const float* __restrict__ W0 = pair ? Wv : Wq;
  const float* __restrict__ W1 = pair ? Wg : Wk;
  __shared__ float xT[128][68];          // [k][t]
  {
    const int j = tid & 127;             // k
    const int half = tid >> 7;
    #pragma unroll 4
    for (int m = 0; m < 32; ++m) {
      const int t = half*32 + m;
      xT[j][t] = x[(m0+t)*D_ + j];
    }
  }
  __syncthreads();
  const int ty = tid >> 4;               // 16 groups x 4 tokens
  const int tx = tid & 15;               // 16 groups x 4 cols
  float acc0[4][4], acc1[4][4];
  #pragma unroll
  for (int i = 0; i < 4; ++i)
    #pragma unroll
    for (int j = 0; j < 4; ++j) { acc0[i][j] = 0.f; acc1[i][j] = 0.f; }
  for (int k = 0; k < 128; ++k) {
    const float4 a  = *(const float4*)&xT[k][ty*4];
    const float4 w0 = *(const float4*)&W0[k*D_ + c0 + tx*4];
    const float4 w1 = *(const float4*)&W1[k*D_ + c0 + tx*4];
    const float av[4] = {a.x, a.y, a.z, a.w};
    #pragma unroll
    for (int i = 0; i < 4; ++i) {
      acc0[i][0] += av[i]*w0.x; acc0[i][1] += av[i]*w0.y;
      acc0[i][2] += av[i]*w0.z; acc0[i][3] += av[i]*w0.w;
      acc1[i][0] += av[i]*w1.x; acc1[i][1] += av[i]*w1.y;
      acc1[i][2] += av[i]*w1.z; acc1[i][3] += av[i]*w1.w;
    }
  }
  if (pair == 0) {
    #pragma unroll
    for (int i = 0; i < 4; ++i) {
      const int row = m0 + ty*4 + i;
      float4 qo, ko;
      float* q = &qo.x; float* kk = &ko.x;
      #pragma unroll
      for (int j = 0; j < 4; ++j) {
        const float qv = acc0[i][j], kv = acc1[i][j];
        q[j]  = (qv > 0.f) ? (qv + 1.f) : expf(qv);
        kk[j] = (kv > 0.f) ? (kv + 1.f) : expf(kv);
      }
      *(float4*)&Qp[row*H_ + c0 + tx*4] = qo;
      *(float4*)&Kp[row*H_ + c0 + tx*4] = ko;
    }
  } else {
    const float4 bg4 = *(const float4*)&bg[c0 + tx*4];
    const float bgv[4] = {bg4.x, bg4.y, bg4.z, bg4.w};
    #pragma unroll
    for (int i = 0; i < 4; ++i) {
      const int row = m0 + ty*4 + i;
      float4 vo; float* v = &vo.x;
      #pragma unroll
      for (int j = 0; j < 4; ++j) {
        const float gv = 1.f / (1.f + expf(-(acc1[i][j] + bgv[j])));
        v[j] = acc0[i][j] * gv;
      }
      *(float4*)&Vg[row*D_ + c0 + tx*4] = vo;
    }
  }
}

// ---------------- Per-chunk KV = Kp_c^T @ Vg_c (128x128) + Ksum_c ----------------
__global__ __launch_bounds__(256) void k_chunkkv2(const float* __restrict__ Kp,
    const float* __restrict__ Vg, float* __restrict__ KV,
    float* __restrict__ Ksum) {
  const int c = blockIdx.x;
  const int tid = threadIdx.x;
  const int hq = tid >> 4, dq = tid & 15;
  const int base = c * CHUNK;
  __shared__ float ks[32][132];
  __shared__ float vs[32][132];
  float acc[8][8];
  #pragma unroll
  for (int i = 0; i < 8; ++i)
    #pragma unroll
    for (int j = 0; j < 8; ++j) acc[i][j] = 0.f;
  float kspart = 0.f;
  for (int t0 = 0; t0 < CHUNK; t0 += 32) {
    for (int i = tid; i < 32*D_; i += 256) {
      const int tt = i >> 7, kk = i & 127;
      ks[tt][kk] = Kp[(base+t0+tt)*H_ + kk];
      vs[tt][kk] = Vg[(base+t0+tt)*D_ + kk];
    }
    __syncthreads();
    for (int t = 0; t < 32; ++t) {
      float kh[8], vd[8];
      *(float4*)&kh[0] = *(const float4*)&ks[t][hq*8];
      *(float4*)&kh[4] = *(const float4*)&ks[t][hq*8+4];
      *(float4*)&vd[0] = *(const float4*)&vs[t][dq*8];
      *(float4*)&vd[4] = *(const float4*)&vs[t][dq*8+4];
      #pragma unroll
      for (int i = 0; i < 8; ++i)
        #pragma unroll
        for (int j = 0; j < 8; ++j) acc[i][j] += kh[i]*vd[j];
    }
    if (tid < H_) {
      #pragma unroll 8
      for (int t = 0; t < 32; ++t) kspart += ks[t][tid];
    }
    __syncthreads();
  }
  float* outp = KV + (size_t)c*(H_*D_);
  #pragma unroll
  for (int i = 0; i < 8; ++i) {
    const int h = hq*8+i;
    *(float4*)&outp[h*D_ + dq*8]   = make_float4(acc[i][0],acc[i][1],acc[i][2],acc[i][3]);
    *(float4*)&outp[h*D_ + dq*8+4] = make_float4(acc[i][4],acc[i][5],acc[i][6],acc[i][7]);
  }
  if (tid < H_) Ksum[c*H_ + tid] = kspart;
}

// ---------------- Exclusive prefix over chunks, pipelined ----------------
__global__ __launch_bounds__(128) void k_prefix2(float* __restrict__ KV,
    float* __restrict__ Ksum) {
  const int tid = threadIdx.x;
  if (blockIdx.x < 256) {
    const int b = blockIdx.x >> 7;
    const int e = (blockIdx.x & 127) * 128 + tid;
    const size_t base = (size_t)b*NCB*(H_*D_) + e;
    float run = 0.f;
    for (int c0 = 0; c0 < NCB; c0 += 16) {
      float v[16];
      #pragma unroll
      for (int i = 0; i < 16; ++i) v[i] = KV[base + (size_t)(c0+i)*(H_*D_)];
      #pragma unroll
      for (int i = 0; i < 16; ++i) {
        const float t = v[i];
        KV[base + (size_t)(c0+i)*(H_*D_)] = run;
        run += t;
      }
    }
  } else {
    const int b = blockIdx.x - 256;
    const int h = tid;                   // 0..127
    float run = 0.f;
    for (int c0 = 0; c0 < NCB; c0 += 16) {
      float v[16];
      #pragma unroll
      for (int i = 0; i < 16; ++i) v[i] = Ksum[(b*NCB + c0+i)*H_ + h];
      #pragma unroll
      for (int i = 0; i < 16; ++i) {
        const float t = v[i];
        Ksum[(b*NCB + c0+i)*H_ + h] = run;
        run += t;
      }
    }
  }
}

// ---------------- Masked intra-chunk scores (64x64) + rowsums ----------------
__global__ __launch_bounds__(256) void k_scores2(const float* __restrict__ Qp,
    const float* __restrict__ Kp, float* __restrict__ A,
    float* __restrict__ rowsum) {
  const int c = blockIdx.x, tid = threadIdx.x;
  const int ty = tid >> 4, tx = tid & 15;  // 16x16 groups, 4x4 per thread
  const int base = c * CHUNK;
  __shared__ float qT[32][68];
  __shared__ float kT[32][68];
  __shared__ float rbuf[CHUNK][17];
  float acc[4][4];
  #pragma unroll
  for (int i = 0; i < 4; ++i)
    #pragma unroll
    for (int j = 0; j < 4; ++j) acc[i][j] = 0.f;
  for (int k0 = 0; k0 < H_; k0 += 32) {
    for (int i = tid; i < 32*CHUNK; i += 256) {
      const int kk = i & 31, t = i >> 5;
      qT[kk][t] = Qp[(base+t)*H_ + k0 + kk];
      kT[kk][t] = Kp[(base+t)*H_ + k0 + kk];
    }
    __syncthreads();
    for (int k = 0; k < 32; ++k) {
      const float4 a = *(const float4*)&qT[k][ty*4];
      const float4 bb = *(const float4*)&kT[k][tx*4];
      const float av[4] = {a.x,a.y,a.z,a.w};
      #pragma unroll
      for (int i = 0; i < 4; ++i) {
        acc[i][0] += av[i]*bb.x; acc[i][1] += av[i]*bb.y;
        acc[i][2] += av[i]*bb.z; acc[i][3] += av[i]*bb.w;
      }
    }
    __syncthreads();
  }
  float rs[4];
  #pragma unroll
  for (int i = 0; i < 4; ++i) {
    const int t = ty*4+i;
    rs[i] = 0.f;
    #pragma unroll
    for (int j = 0; j < 4; ++j) {
      if (tx*4+j > t) acc[i][j] = 0.f;
      rs[i] += acc[i][j];
    }
  }
  float* Ac = A + (size_t)c*(CHUNK*CHUNK);
  #pragma unroll
  for (int i = 0; i < 4; ++i) {
    const int t = ty*4+i;
    *(float4*)&Ac[t*CHUNK + tx*4] = make_float4(acc[i][0],acc[i][1],acc[i][2],acc[i][3]);
    rbuf[t][tx] = rs[i];
  }
  __syncthreads();
  if (tid < CHUNK) {
    float s = 0.f;
    #pragma unroll
    for (int x2 = 0; x2 < 16; ++x2) s += rbuf[tid][x2];
    rowsum[c*CHUNK + tid] = s;
  }
}

// ---------------- numerator = [A|Qp]@[Vg;Sprev], denom, attn ----------------
__global__ __launch_bounds__(256) void k_attnout2(const float* __restrict__ A,
    const float* __restrict__ Vg, const float* __restrict__ Qp,
    const float* __restrict__ KV, const float* __restrict__ Ksum,
    const float* __restrict__ rowsum, float* __restrict__ attn) {
  const int c = blockIdx.x, tid = threadIdx.x;
  const int ty = tid >> 5, tx = tid & 31;  // 8 groups x 8 tok, 32 groups x 4 d
  const int base = c * CHUNK;
  __shared__ float aT[32][72];
  __shared__ float bs[32][132];
  __shared__ float kss[32];
  float acc[8][4];
  float dsum[8];
  #pragma unroll
  for (int i = 0; i < 8; ++i) {
    dsum[i] = 0.f;
    #pragma unroll
    for (int j = 0; j < 4; ++j) acc[i][j] = 0.f;
  }
  const float* Ac  = A  + (size_t)c*(CHUNK*CHUNK);
  const float* KVc = KV + (size_t)c*(H_*D_);
  for (int k0 = 0; k0 < CHUNK + H_; k0 += 32) {
    for (int i = tid; i < 32*CHUNK; i += 256) {
      const int kk = i & 31, t = i >> 5;
      const int k = k0 + kk;
      aT[kk][t] = (k < CHUNK) ? Ac[t*CHUNK + k] : Qp[(base+t)*H_ + (k-CHUNK)];
    }
    for (int i = tid; i < 32*D_; i += 256) {
      const int kk = i >> 7, d = i & 127;
      const int k = k0 + kk;
      bs[kk][d] = (k < CHUNK) ? Vg[(base+k)*D_ + d] : KVc[(size_t)(k-CHUNK)*D_ + d];
    }
    if (tid < 32) {
      const int k = k0 + tid;
      kss[tid] = (k >= CHUNK) ? Ksum[c*H_ + (k-CHUNK)] : 0.f;
    }
    __syncthreads();
    for (int k = 0; k < 32; ++k) {
      float a8[8];
      *(float4*)&a8[0] = *(const float4*)&aT[k][ty*8];
      *(float4*)&a8[4] = *(const float4*)&aT[k][ty*8+4];
      const float4 bv = *(const float4*)&bs[k][tx*4];
      const float ksv = kss[k];
      #pragma unroll
      for (int i = 0; i < 8; ++i) {
        dsum[i] += a8[i]*ksv;
        acc[i][0] += a8[i]*bv.x; acc[i][1] += a8[i]*bv.y;
        acc[i][2] += a8[i]*bv.z; acc[i][3] += a8[i]*bv.w;
      }
    }
    __syncthreads();
  }
  #pragma unroll
  for (int i = 0; i < 8; ++i) {
    const int t = ty*8+i;
    const float den = fmaxf(rowsum[c*CHUNK + t] + dsum[i], EPS_ATTN);
    const float inv = 1.f/den;
    *(float4*)&attn[(size_t)(base+t)*D_ + tx*4] =
      make_float4(acc[i][0]*inv, acc[i][1]*inv, acc[i][2]*inv, acc[i][3]*inv);
  }
}

// ---------------- out = LN2(tokens + 0.1*(attn@Wo)) ----------------
__global__ __launch_bounds__(256) void k_outln2(const float* __restrict__ attn,
    const float* __restrict__ Wo, const float* __restrict__ tokens,
    const float* __restrict__ g2, const float* __restrict__ b2,
    float* __restrict__ out) {
  const int tid = threadIdx.x;
  const int m0 = blockIdx.x * 64;
  __shared__ float aT[128][68];
  {
    const int j = tid & 127;
    const int half = tid >> 7;
    #pragma unroll 4
    for (int m = 0; m < 32; ++m) {
      const int t = half*32 + m;
      aT[j][t] = attn[(m0+t)*D_ + j];
    }
  }
  __syncthreads();
  const int ty = tid >> 5, tx = tid & 31;  // 8 x 8 tok, 32 x 4 col
  float acc[8][4];
  #pragma unroll
  for (int i = 0; i < 8; ++i)
    #pragma unroll
    for (int j = 0; j < 4; ++j) acc[i][j] = 0.f;
  for (int k = 0; k < 128; ++k) {
    float a8[8];
    *(float4*)&a8[0] = *(const float4*)&aT[k][ty*8];
    *(float4*)&a8[4] = *(const float4*)&aT[k][ty*8+4];
    const float4 w = *(const float4*)&Wo[k*D_ + tx*4];
    #pragma unroll
    for (int i = 0; i < 8; ++i) {
      acc[i][0] += a8[i]*w.x; acc[i][1] += a8[i]*w.y;
      acc[i][2] += a8[i]*w.z; acc[i][3] += a8[i]*w.w;
    }
  }
  const float4 gv4 = *(const float4*)&g2[tx*4];
  const float4 bv4 = *(const float4*)&b2[tx*4];
  const float gv[4] = {gv4.x,gv4.y,gv4.z,gv4.w};
  const float bv[4] = {bv4.x,bv4.y,bv4.z,bv4.w};
  #pragma unroll
  for (int i = 0; i < 8; ++i) {
    const int row = m0 + ty*8 + i;
    const float4 tk = *(const float4*)&tokens[row*D_ + tx*4];
    float p[4] = {tk.x + 0.1f*acc[i][0], tk.y + 0.1f*acc[i][1],
                  tk.z + 0.1f*acc[i][2], tk.w + 0.1f*acc[i][3]};
    float s = p[0]+p[1]+p[2]+p[3];
    float q = p[0]*p[0]+p[1]*p[1]+p[2]*p[2]+p[3]*p[3];
    #pragma unroll
    for (int off = 16; off > 0; off >>= 1) {
      s += __shfl_xor(s, off);
      q += __shfl_xor(q, off);
    }
    const float mean = s * (1.0f/D_);
    const float var  = q * (1.0f/D_) - mean*mean;
    const float r = rsqrtf(var + LN_EPS);
    float4 o;
    o.x = (p[0]-mean)*r*gv[0] + bv[0];
    o.y = (p[1]-mean)*r*gv[1] + bv[1];
    o.z = (p[2]-mean)*r*gv[2] + bv[2];
    o.w = (p[3]-mean)*r*gv[3] + bv[3];
    *(float4*)&out[row*D_ + tx*4] = o;
  }
}

extern "C" void kernel_launch(void* const* d_in, const int* in_sizes, int n_in,
                              void* d_out, int out_size, void* d_ws, size_t ws_size,
                              hipStream_t stream) {
  const float* tokens = (const float*)d_in[0];
  const float* Wq = (const float*)d_in[1];
  const float* Wk = (const float*)d_in[2];
  const float* Wv = (const float*)d_in[3];
  const float* Wg = (const float*)d_in[4];
  const float* bg = (const float*)d_in[5];
  const float* Wo = (const float*)d_in[6];
  const float* g1 = (const float*)d_in[7];
  const float* b1 = (const float*)d_in[8];
  const float* g2 = (const float*)d_in[9];
  const float* b2 = (const float*)d_in[10];

  float* ws = (float*)d_ws;
  const size_t M1 = 1048576;
  float* x      = ws;                    // dead after k_qkvg2; A aliases it
  float* A      = ws;                    // 128 * 64*64 = 0.5M
  float* Qp     = ws + 1*M1;
  float* Kp     = ws + 2*M1;
  float* Vg     = ws + 3*M1;
  float* KV     = ws + 4*M1;             // 128 * 128*128 = 2M
  float* attn   = ws + 6*M1;
  float* rowsum = ws + 7*M1;             // 128*64
  float* Ksum   = ws + 7*M1 + 16384;     // 128*128

  k_ln<<<NTOK, 128, 0, stream>>>(tokens, g1, b1, x);
  k_qkvg2<<<dim3(NTOK/64, 2, 2), 256, 0, stream>>>(x, Wq, Wk, Wv, Wg, bg, Qp, Kp, Vg);
  k_chunkkv2<<<NCHUNKS, 256, 0, stream>>>(Kp, Vg, KV, Ksum);
  k_prefix2<<<258, 128, 0, stream>>>(KV, Ksum);
  k_scores2<<<NCHUNKS, 256, 0, stream>>>(Qp, Kp, A, rowsum);
  k_attnout2<<<NCHUNKS, 256, 0, stream>>>(A, Vg, Qp, KV, Ksum, rowsum, attn);
  k_outln2<<<NTOK/64, 256, 0, stream>>>(attn, Wo, tokens, g2, b2, (float*)d_out);
}

// Round 3
// 124.868 us; speedup vs baseline: 2.4882x; 1.5820x over previous
//
#include <hip/hip_runtime.h>
#include <math.h>

#define T_ 4096
#define D_ 128
#define NTOK 8192
#define CHUNK 64
#define NCB 64        // chunks per batch
#define NCH 128       // total chunks
#define LN_EPS 1e-5f
#define EPS_ATTN 1e-6f

typedef __attribute__((ext_vector_type(8))) short bf16x8;
typedef __attribute__((ext_vector_type(4))) short bf16x4;
typedef __attribute__((ext_vector_type(2))) short bf16x2;
typedef __attribute__((ext_vector_type(4))) float f32x4;

__device__ inline short f2bf(float f) {
  unsigned u = __builtin_bit_cast(unsigned, f);
  u += 0x7fffu + ((u >> 16) & 1u);
  return (short)(u >> 16);
}
__device__ inline float bf2f(short s) {
  unsigned u = ((unsigned)(unsigned short)s) << 16;
  return __builtin_bit_cast(float, u);
}
__device__ inline float phi_(float x) { return x > 0.f ? x + 1.f : __expf(x); }

// ---------------- LN1 -> x bf16 ----------------
__global__ __launch_bounds__(256) void k_prep(const float* __restrict__ in,
    const float* __restrict__ g, const float* __restrict__ b,
    short* __restrict__ xb) {
  const int w = threadIdx.x >> 6, l = threadIdx.x & 63;
  const int tok = blockIdx.x*4 + w;
  const float2 v = *(const float2*)&in[tok*D_ + l*2];
  float s = v.x + v.y, q = v.x*v.x + v.y*v.y;
  #pragma unroll
  for (int off = 32; off; off >>= 1) { s += __shfl_xor(s, off); q += __shfl_xor(q, off); }
  const float mean = s*(1.f/D_);
  const float r = rsqrtf(q*(1.f/D_) - mean*mean + LN_EPS);
  const float2 gg = *(const float2*)&g[l*2];
  const float2 bb = *(const float2*)&b[l*2];
  bf16x2 o;
  o.x = f2bf((v.x-mean)*r*gg.x + bb.x);
  o.y = f2bf((v.y-mean)*r*gg.y + bb.y);
  *(bf16x2*)&xb[tok*D_ + l*2] = o;
}

// ---------------- weights: fp32 [k][n] -> bf16 [n][k] (x5) ----------------
__global__ __launch_bounds__(256) void k_wprep(const float* __restrict__ Wq,
    const float* __restrict__ Wk, const float* __restrict__ Wv,
    const float* __restrict__ Wg, const float* __restrict__ Wo,
    short* __restrict__ WT) {
  const float* W = blockIdx.x==0?Wq: blockIdx.x==1?Wk: blockIdx.x==2?Wv: blockIdx.x==3?Wg:Wo;
  short* out = WT + blockIdx.x*D_*D_;
  __shared__ float lds[128][132];
  const int tid = threadIdx.x;
  #pragma unroll
  for (int it = 0; it < 16; ++it) {
    const int f = it*1024 + tid*4;
    const int k = f >> 7, n = f & 127;
    const float4 v = *(const float4*)&W[f];
    lds[k][n] = v.x; lds[k][n+1] = v.y; lds[k][n+2] = v.z; lds[k][n+3] = v.w;
  }
  __syncthreads();
  #pragma unroll
  for (int it = 0; it < 16; ++it) {
    const int f = it*1024 + tid*4;
    const int n = f >> 7, k = f & 127;
    bf16x4 o;
    o.x = f2bf(lds[k][n]);   o.y = f2bf(lds[k+1][n]);
    o.z = f2bf(lds[k+2][n]); o.w = f2bf(lds[k+3][n]);
    *(bf16x4*)&out[f] = o;
  }
}

// ---------------- QKVG MFMA: block = (64-token tile, weight y) ----------------
// y=0 -> Qp[t][h]=phi ; y=1 -> Kp[t][h]+KpT[h][t]=phi ; y=2 -> VT[d][t] ; y=3 -> GT[d][t]
__global__ __launch_bounds__(256) void k_qkvg(const short* __restrict__ xb,
    const short* __restrict__ WT,
    short* __restrict__ Qp, short* __restrict__ Kp, short* __restrict__ KpT,
    short* __restrict__ VT, short* __restrict__ GT) {
  const int m0 = blockIdx.x * 64;
  const int y = blockIdx.y;
  const int tid = threadIdx.x;
  __shared__ short xs[64][136];
  __shared__ short wsd[128][136];
  const short* W = WT + y*D_*D_;
  #pragma unroll
  for (int u = tid; u < 1024; u += 256) {
    const int r = u >> 4, c8 = (u & 15)*8;
    *(bf16x8*)&xs[r][c8] = *(const bf16x8*)&xb[(m0+r)*D_ + c8];
  }
  #pragma unroll
  for (int u = tid; u < 2048; u += 256) {
    const int r = u >> 4, c8 = (u & 15)*8;
    *(bf16x8*)&wsd[r][c8] = *(const bf16x8*)&W[r*D_ + c8];
  }
  __syncthreads();
  const int w = tid >> 6, l = tid & 63;
  const int i = l & 15, q = l >> 4;
  f32x4 acc[4][2];
  #pragma unroll
  for (int mt = 0; mt < 4; ++mt)
    #pragma unroll
    for (int nt = 0; nt < 2; ++nt) acc[mt][nt] = (f32x4){0.f,0.f,0.f,0.f};
  #pragma unroll
  for (int kk = 0; kk < 4; ++kk) {
    bf16x8 a[4], bfr[2];
    #pragma unroll
    for (int mt = 0; mt < 4; ++mt) a[mt] = *(const bf16x8*)&xs[mt*16+i][kk*32+q*8];
    #pragma unroll
    for (int nt = 0; nt < 2; ++nt) bfr[nt] = *(const bf16x8*)&wsd[w*32+nt*16+i][kk*32+q*8];
    #pragma unroll
    for (int mt = 0; mt < 4; ++mt)
      #pragma unroll
      for (int nt = 0; nt < 2; ++nt)
        acc[mt][nt] = __builtin_amdgcn_mfma_f32_16x16x32_bf16(a[mt], bfr[nt], acc[mt][nt], 0, 0, 0);
  }
  if (y == 0) {
    #pragma unroll
    for (int mt = 0; mt < 4; ++mt)
      #pragma unroll
      for (int nt = 0; nt < 2; ++nt) {
        const int h = w*32 + nt*16 + i;
        #pragma unroll
        for (int r = 0; r < 4; ++r) {
          const int t = m0 + mt*16 + 4*q + r;
          Qp[t*D_ + h] = f2bf(phi_(acc[mt][nt][r]));
        }
      }
  } else if (y == 1) {
    #pragma unroll
    for (int mt = 0; mt < 4; ++mt)
      #pragma unroll
      for (int nt = 0; nt < 2; ++nt) {
        const int h = w*32 + nt*16 + i;
        const int t0 = m0 + mt*16 + 4*q;
        bf16x4 o;
        #pragma unroll
        for (int r = 0; r < 4; ++r) {
          const float pv = phi_(acc[mt][nt][r]);
          const short bv = f2bf(pv);
          Kp[(t0+r)*D_ + h] = bv;
          o[r] = bv;
        }
        *(bf16x4*)&KpT[h*NTOK + t0] = o;
      }
  } else {
    short* dst = (y == 2) ? VT : GT;
    #pragma unroll
    for (int mt = 0; mt < 4; ++mt)
      #pragma unroll
      for (int nt = 0; nt < 2; ++nt) {
        const int h = w*32 + nt*16 + i;
        const int t0 = m0 + mt*16 + 4*q;
        bf16x4 o;
        #pragma unroll
        for (int r = 0; r < 4; ++r) o[r] = f2bf(acc[mt][nt][r]);
        *(bf16x4*)&dst[h*NTOK + t0] = o;
      }
  }
}

// ---------------- per-chunk KV^T[d][h] = sum_t Vg[t][d]*Kp[t][h], + Ksum ----------------
__global__ __launch_bounds__(256) void k_chunkkv(const short* __restrict__ KpT,
    const short* __restrict__ VT, const short* __restrict__ GT,
    const float* __restrict__ bg,
    float* __restrict__ KVT, float* __restrict__ Ksum) {
  const int c = blockIdx.x, hh = blockIdx.y;
  const int tid = threadIdx.x;
  const int tb = c*CHUNK;
  __shared__ short vgl[128][72];
  __shared__ short kpl[64][72];
  __shared__ float ksp[64][5];
  #pragma unroll
  for (int u = tid; u < 1024; u += 256) {
    const int d = u >> 3, c8 = (u & 7)*8;
    bf16x8 v  = *(const bf16x8*)&VT[d*NTOK + tb + c8];
    bf16x8 g8 = *(const bf16x8*)&GT[d*NTOK + tb + c8];
    const float bgd = bg[d];
    bf16x8 o;
    #pragma unroll
    for (int j = 0; j < 8; ++j) {
      const float gv = 1.f/(1.f + __expf(-(bf2f(g8[j]) + bgd)));
      o[j] = f2bf(bf2f(v[j]) * gv);
    }
    *(bf16x8*)&vgl[d][c8] = o;
  }
  #pragma unroll
  for (int u = tid; u < 512; u += 256) {
    const int h = u >> 3, c8 = (u & 7)*8;
    *(bf16x8*)&kpl[h][c8] = *(const bf16x8*)&KpT[(hh*64+h)*NTOK + tb + c8];
  }
  __syncthreads();
  const int w = tid >> 6, l = tid & 63, i = l & 15, q = l >> 4;
  f32x4 acc[2][4];
  #pragma unroll
  for (int mt = 0; mt < 2; ++mt)
    #pragma unroll
    for (int nt = 0; nt < 4; ++nt) acc[mt][nt] = (f32x4){0.f,0.f,0.f,0.f};
  #pragma unroll
  for (int kk = 0; kk < 2; ++kk) {
    bf16x8 a[2], bb[4];
    #pragma unroll
    for (int mt = 0; mt < 2; ++mt) a[mt] = *(const bf16x8*)&vgl[(2*w+mt)*16+i][kk*32+q*8];
    #pragma unroll
    for (int nt = 0; nt < 4; ++nt) bb[nt] = *(const bf16x8*)&kpl[nt*16+i][kk*32+q*8];
    #pragma unroll
    for (int mt = 0; mt < 2; ++mt)
      #pragma unroll
      for (int nt = 0; nt < 4; ++nt)
        acc[mt][nt] = __builtin_amdgcn_mfma_f32_16x16x32_bf16(a[mt], bb[nt], acc[mt][nt], 0, 0, 0);
  }
  float* KVc = KVT + (size_t)c*16384;
  #pragma unroll
  for (int mt = 0; mt < 2; ++mt)
    #pragma unroll
    for (int nt = 0; nt < 4; ++nt)
      #pragma unroll
      for (int r = 0; r < 4; ++r) {
        const int d = (2*w+mt)*16 + 4*q + r;
        const int h = hh*64 + nt*16 + i;
        KVc[d*128 + h] = acc[mt][nt][r];
      }
  {
    const int h = tid >> 2, part = tid & 3;
    float s = 0.f;
    #pragma unroll
    for (int t = 0; t < 16; ++t) s += bf2f(kpl[h][part*16 + t]);
    ksp[h][part] = s;
  }
  __syncthreads();
  if (tid < 64)
    Ksum[c*128 + hh*64 + tid] = ksp[tid][0]+ksp[tid][1]+ksp[tid][2]+ksp[tid][3];
}

// ---------------- exclusive chunk prefix: KVT fp32 -> KVTb bf16 ; Ksum in place ----------------
__global__ __launch_bounds__(256) void k_prefix(const float* __restrict__ KVT,
    short* __restrict__ KVTb, float* __restrict__ Ksum) {
  const int tid = threadIdx.x;
  if (blockIdx.x < 128) {
    const int b = blockIdx.x >> 6;
    const int e = (blockIdx.x & 63)*256 + tid;
    const size_t base = (size_t)b*NCB*16384 + e;
    float run = 0.f;
    #pragma unroll 8
    for (int c = 0; c < NCB; ++c) {
      const float v = KVT[base + (size_t)c*16384];
      KVTb[base + (size_t)c*16384] = f2bf(run);
      run += v;
    }
  } else if (tid < 128) {
    const int b = blockIdx.x - 128;
    float run = 0.f;
    #pragma unroll 8
    for (int c = 0; c < NCB; ++c) {
      const int idx = (b*NCB + c)*128 + tid;
      const float v = Ksum[idx];
      Ksum[idx] = run;
      run += v;
    }
  }
}

// ---------------- intra-chunk masked scores A (bf16) + full denominator ----------------
__global__ __launch_bounds__(256) void k_scores(const short* __restrict__ Qp,
    const short* __restrict__ Kp, const float* __restrict__ Ksum,
    short* __restrict__ A, float* __restrict__ den) {
  const int c = blockIdx.x, tid = threadIdx.x;
  const int tb = c*CHUNK;
  __shared__ short qpl[64][136], kpl[64][136];
  __shared__ float ksl[128], rsl[64];
  #pragma unroll
  for (int u = tid; u < 1024; u += 256) {
    const int t = u >> 4, c8 = (u & 15)*8;
    *(bf16x8*)&qpl[t][c8] = *(const bf16x8*)&Qp[(tb+t)*D_ + c8];
    *(bf16x8*)&kpl[t][c8] = *(const bf16x8*)&Kp[(tb+t)*D_ + c8];
  }
  if (tid < 128) ksl[tid] = Ksum[c*128 + tid];
  __syncthreads();
  const int w = tid >> 6, l = tid & 63, i = l & 15, q = l >> 4;
  f32x4 acc[4];
  #pragma unroll
  for (int nt = 0; nt < 4; ++nt) acc[nt] = (f32x4){0.f,0.f,0.f,0.f};
  #pragma unroll
  for (int kk = 0; kk < 4; ++kk) {
    bf16x8 a = *(const bf16x8*)&qpl[w*16+i][kk*32+q*8];
    for (int nt = 0; nt <= w; ++nt) {
      bf16x8 bb = *(const bf16x8*)&kpl[nt*16+i][kk*32+q*8];
      acc[nt] = __builtin_amdgcn_mfma_f32_16x16x32_bf16(a, bb, acc[nt], 0, 0, 0);
    }
  }
  short* Ac = A + c*4096;
  float rs[4] = {0.f,0.f,0.f,0.f};
  #pragma unroll
  for (int nt = 0; nt < 4; ++nt) {
    #pragma unroll
    for (int r = 0; r < 4; ++r) {
      const int t = w*16 + 4*q + r;
      const int s = nt*16 + i;
      const float v = (nt <= w && s <= t) ? acc[nt][r] : 0.f;
      rs[r] += v;
      Ac[t*64 + s] = f2bf(v);
    }
  }
  #pragma unroll
  for (int r = 0; r < 4; ++r) {
    #pragma unroll
    for (int off = 1; off < 16; off <<= 1) rs[r] += __shfl_xor(rs[r], off);
  }
  if (i == 0) {
    #pragma unroll
    for (int r = 0; r < 4; ++r) rsl[w*16 + 4*q + r] = rs[r];
  }
  __syncthreads();
  if (tid < 64) {
    float dot = 0.f;
    #pragma unroll 8
    for (int h = 0; h < 128; ++h) dot += bf2f(qpl[tid][h]) * ksl[h];
    den[c*64 + tid] = rsl[tid] + dot;
  }
}

// ---------------- num = [A|Qp] @ [Vg ; S_prev], divide by den -> attn bf16 ----------------
__global__ __launch_bounds__(256) void k_attnout(const short* __restrict__ Aintra,
    const short* __restrict__ Qp, const short* __restrict__ VT,
    const short* __restrict__ GT, const float* __restrict__ bg,
    const short* __restrict__ KVTb, const float* __restrict__ den,
    short* __restrict__ attn) {
  const int c = blockIdx.x, dh = blockIdx.y, tid = threadIdx.x;
  const int tb = c*CHUNK;
  __shared__ short at[64][200], bt[64][200];
  __shared__ float denl[64];
  const short* Ac = Aintra + c*4096;
  #pragma unroll
  for (int u = tid; u < 512; u += 256) {
    const int t = u >> 3, c8 = (u & 7)*8;
    *(bf16x8*)&at[t][c8] = *(const bf16x8*)&Ac[t*64 + c8];
  }
  #pragma unroll
  for (int u = tid; u < 1024; u += 256) {
    const int t = u >> 4, c8 = (u & 15)*8;
    *(bf16x8*)&at[t][64 + c8] = *(const bf16x8*)&Qp[(tb+t)*D_ + c8];
  }
  #pragma unroll
  for (int u = tid; u < 512; u += 256) {
    const int dd = u >> 3, c8 = (u & 7)*8;
    const int d = dh*64 + dd;
    bf16x8 v  = *(const bf16x8*)&VT[d*NTOK + tb + c8];
    bf16x8 g8 = *(const bf16x8*)&GT[d*NTOK + tb + c8];
    const float bgd = bg[d];
    bf16x8 o;
    #pragma unroll
    for (int j = 0; j < 8; ++j) {
      const float gv = 1.f/(1.f + __expf(-(bf2f(g8[j]) + bgd)));
      o[j] = f2bf(bf2f(v[j]) * gv);
    }
    *(bf16x8*)&bt[dd][c8] = o;
  }
  #pragma unroll
  for (int u = tid; u < 1024; u += 256) {
    const int dd = u >> 4, c8 = (u & 15)*8;
    *(bf16x8*)&bt[dd][64 + c8] = *(const bf16x8*)&KVTb[(size_t)c*16384 + (dh*64+dd)*128 + c8];
  }
  if (tid < 64) denl[tid] = den[c*64 + tid];
  __syncthreads();
  const int w = tid >> 6, l = tid & 63, i = l & 15, q = l >> 4;
  f32x4 acc[4];
  #pragma unroll
  for (int nt = 0; nt < 4; ++nt) acc[nt] = (f32x4){0.f,0.f,0.f,0.f};
  #pragma unroll
  for (int kk = 0; kk < 6; ++kk) {
    bf16x8 a = *(const bf16x8*)&at[w*16+i][kk*32+q*8];
    #pragma unroll
    for (int nt = 0; nt < 4; ++nt) {
      bf16x8 bb = *(const bf16x8*)&bt[nt*16+i][kk*32+q*8];
      acc[nt] = __builtin_amdgcn_mfma_f32_16x16x32_bf16(a, bb, acc[nt], 0, 0, 0);
    }
  }
  #pragma unroll
  for (int r = 0; r < 4; ++r) {
    const int t = w*16 + 4*q + r;
    const float inv = 1.f / fmaxf(denl[t], EPS_ATTN);
    #pragma unroll
    for (int nt = 0; nt < 4; ++nt)
      attn[(size_t)(tb+t)*D_ + dh*64 + nt*16 + i] = f2bf(acc[nt][r] * inv);
  }
}

// ---------------- out = LN2(tokens + 0.1*(attn@Wo)) ----------------
__global__ __launch_bounds__(256) void k_outln2(const short* __restrict__ attn,
    const short* __restrict__ WoT, const float* __restrict__ tokens,
    const float* __restrict__ g2, const float* __restrict__ b2,
    float* __restrict__ out) {
  const int m0 = blockIdx.x*32, tid = threadIdx.x;
  __shared__ short al[32][136], wl[128][136];
  __shared__ float tl[32][132];
  __shared__ float suml[32][2], ssql[32][2];
  __shared__ float meanl[32], rstdl[32];
  __shared__ float gl[128], bl2[128];
  #pragma unroll
  for (int u = tid; u < 512; u += 256) {
    const int t = u >> 4, c8 = (u & 15)*8;
    *(bf16x8*)&al[t][c8] = *(const bf16x8*)&attn[(m0+t)*D_ + c8];
  }
  #pragma unroll
  for (int u = tid; u < 2048; u += 256) {
    const int n = u >> 4, c8 = (u & 15)*8;
    *(bf16x8*)&wl[n][c8] = *(const bf16x8*)&WoT[n*D_ + c8];
  }
  #pragma unroll
  for (int u = tid; u < 1024; u += 256) {
    const int t = u >> 5, c4 = (u & 31)*4;
    *(float4*)&tl[t][c4] = *(const float4*)&tokens[(m0+t)*D_ + c4];
  }
  if (tid < 128) { gl[tid] = g2[tid]; bl2[tid] = b2[tid]; }
  __syncthreads();
  const int w = tid >> 6, l = tid & 63, i = l & 15, q = l >> 4;
  const int mt = w >> 1, nh = w & 1;
  f32x4 acc[4];
  #pragma unroll
  for (int j = 0; j < 4; ++j) acc[j] = (f32x4){0.f,0.f,0.f,0.f};
  #pragma unroll
  for (int kk = 0; kk < 4; ++kk) {
    bf16x8 a = *(const bf16x8*)&al[mt*16+i][kk*32+q*8];
    #pragma unroll
    for (int j = 0; j < 4; ++j) {
      bf16x8 bb = *(const bf16x8*)&wl[(nh*4+j)*16+i][kk*32+q*8];
      acc[j] = __builtin_amdgcn_mfma_f32_16x16x32_bf16(a, bb, acc[j], 0, 0, 0);
    }
  }
  float p[4][4], ps[4], qs[4];
  #pragma unroll
  for (int r = 0; r < 4; ++r) {
    const int t = mt*16 + 4*q + r;
    ps[r] = 0.f; qs[r] = 0.f;
    #pragma unroll
    for (int j = 0; j < 4; ++j) {
      const int col = nh*64 + j*16 + i;
      const float v = tl[t][col] + 0.1f*acc[j][r];
      p[r][j] = v; ps[r] += v; qs[r] += v*v;
    }
  }
  #pragma unroll
  for (int r = 0; r < 4; ++r) {
    #pragma unroll
    for (int off = 1; off < 16; off <<= 1) {
      ps[r] += __shfl_xor(ps[r], off);
      qs[r] += __shfl_xor(qs[r], off);
    }
  }
  if (i == 0) {
    #pragma unroll
    for (int r = 0; r < 4; ++r) {
      suml[mt*16+4*q+r][nh] = ps[r];
      ssql[mt*16+4*q+r][nh] = qs[r];
    }
  }
  __syncthreads();
  if (tid < 32) {
    const float s = suml[tid][0] + suml[tid][1];
    const float qq = ssql[tid][0] + ssql[tid][1];
    const float mean = s*(1.f/D_);
    meanl[tid] = mean;
    rstdl[tid] = rsqrtf(qq*(1.f/D_) - mean*mean + LN_EPS);
  }
  __syncthreads();
  #pragma unroll
  for (int r = 0; r < 4; ++r) {
    const int t = mt*16 + 4*q + r;
    const float mean = meanl[t], rr = rstdl[t];
    #pragma unroll
    for (int j = 0; j < 4; ++j) {
      const int col = nh*64 + j*16 + i;
      out[(m0+t)*D_ + col] = (p[r][j]-mean)*rr*gl[col] + bl2[col];
    }
  }
}

extern "C" void kernel_launch(void* const* d_in, const int* in_sizes, int n_in,
                              void* d_out, int out_size, void* d_ws, size_t ws_size,
                              hipStream_t stream) {
  const float* tokens = (const float*)d_in[0];
  const float* Wq = (const float*)d_in[1];
  const float* Wk = (const float*)d_in[2];
  const float* Wv = (const float*)d_in[3];
  const float* Wg = (const float*)d_in[4];
  const float* bg = (const float*)d_in[5];
  const float* Wo = (const float*)d_in[6];
  const float* g1 = (const float*)d_in[7];
  const float* b1 = (const float*)d_in[8];
  const float* g2 = (const float*)d_in[9];
  const float* b2 = (const float*)d_in[10];

  char* base = (char*)d_ws;
  short* xb     = (short*)(base);                       // 2MB
  short* Qp     = (short*)(base + (2u<<20));            // 2MB
  short* Kp     = (short*)(base + (4u<<20));            // 2MB
  short* KpT    = (short*)(base + (6u<<20));            // 2MB
  short* VT     = (short*)(base + (8u<<20));            // 2MB
  short* GT     = (short*)(base + (10u<<20));           // 2MB
  short* attn   = (short*)(base + (12u<<20));           // 2MB
  short* KVTb   = (short*)(base + (14u<<20));           // 4MB
  short* Aintra = (short*)(base + (18u<<20));           // 1MB
  short* WT     = (short*)(base + (19u<<20));           // 160KB (5 mats)
  float* den    = (float*)(base + (19u<<20) + (512u<<10)); // 32KB
  float* Ksum   = (float*)(base + (19u<<20) + (768u<<10)); // 64KB
  float* KVT    = (float*)(base + (20u<<20));           // 8MB

  short* WoT = WT + 4*D_*D_;

  k_prep<<<NTOK/4, 256, 0, stream>>>(tokens, g1, b1, xb);
  k_wprep<<<5, 256, 0, stream>>>(Wq, Wk, Wv, Wg, Wo, WT);
  k_qkvg<<<dim3(NTOK/64, 4), 256, 0, stream>>>(xb, WT, Qp, Kp, KpT, VT, GT);
  k_chunkkv<<<dim3(NCH, 2), 256, 0, stream>>>(KpT, VT, GT, bg, KVT, Ksum);
  k_prefix<<<130, 256, 0, stream>>>(KVT, KVTb, Ksum);
  k_scores<<<NCH, 256, 0, stream>>>(Qp, Kp, Ksum, Aintra, den);
  k_attnout<<<dim3(NCH, 2), 256, 0, stream>>>(Aintra, Qp, VT, GT, bg, KVTb, den, attn);
  k_outln2<<<NTOK/32, 256, 0, stream>>>(attn, WoT, tokens, g2, b2, (float*)d_out);
}

// Round 4
// 120.273 us; speedup vs baseline: 2.5832x; 1.0382x over previous
//
#include <hip/hip_runtime.h>
#include <math.h>

#define T_ 4096
#define D_ 128
#define NTOK 8192
#define CHUNK 64
#define NCB 64        // chunks per batch
#define NCH 128       // total chunks
#define LN_EPS 1e-5f
#define EPS_ATTN 1e-6f

typedef __attribute__((ext_vector_type(8))) short bf16x8;
typedef __attribute__((ext_vector_type(4))) short bf16x4;
typedef __attribute__((ext_vector_type(4))) float f32x4;

__device__ inline short f2bf(float f) {
  unsigned u = __builtin_bit_cast(unsigned, f);
  u += 0x7fffu + ((u >> 16) & 1u);
  return (short)(u >> 16);
}
__device__ inline float bf2f(short s) {
  unsigned u = ((unsigned)(unsigned short)s) << 16;
  return __builtin_bit_cast(float, u);
}
__device__ inline float phi_(float x) { return x > 0.f ? x + 1.f : __expf(x); }

// ============ K1: fused LN1 + W^T staging + QKVG GEMMs ============
// y=0: Qp[t][h]=phi(x@Wq) ; y=1: Kp[t][h]+KpT[h][t]=phi(x@Wk)
// y=2: VgT[d][t] = (x@Wv)*sigmoid(x@Wg+bg)   (two GEMMs, wsd restaged)
__global__ __launch_bounds__(256) void k_qkvg(const float* __restrict__ tokens,
    const float* __restrict__ Wq, const float* __restrict__ Wk,
    const float* __restrict__ Wv, const float* __restrict__ Wg,
    const float* __restrict__ g1, const float* __restrict__ b1,
    const float* __restrict__ bg,
    short* __restrict__ Qp, short* __restrict__ Kp, short* __restrict__ KpT,
    short* __restrict__ VgT) {
  const int m0 = blockIdx.x * 64;
  const int y = blockIdx.y;
  const int tid = threadIdx.x;
  const int w = tid >> 6, l = tid & 63;
  __shared__ short xs[64][136];
  __shared__ short wsd[128][136];

  // ---- LN1 for this 64-token tile -> xs (bf16) ----
  {
    const int half = l >> 5;           // token parity within pair
    const int c4 = (l & 31) * 4;
    float4 tv[8];
    #pragma unroll
    for (int it = 0; it < 8; ++it) {
      const int t = m0 + w*16 + it*2 + half;
      tv[it] = *(const float4*)&tokens[t*D_ + c4];
    }
    const float4 gg = *(const float4*)&g1[c4];
    const float4 bb = *(const float4*)&b1[c4];
    #pragma unroll
    for (int it = 0; it < 8; ++it) {
      const float4 v = tv[it];
      float s = v.x+v.y+v.z+v.w;
      float q = v.x*v.x+v.y*v.y+v.z*v.z+v.w*v.w;
      #pragma unroll
      for (int off = 1; off < 32; off <<= 1) {
        s += __shfl_xor(s, off); q += __shfl_xor(q, off);
      }
      const float mean = s*(1.f/D_);
      const float r = rsqrtf(q*(1.f/D_) - mean*mean + LN_EPS);
      bf16x4 o;
      o.x = f2bf((v.x-mean)*r*gg.x + bb.x);
      o.y = f2bf((v.y-mean)*r*gg.y + bb.y);
      o.z = f2bf((v.z-mean)*r*gg.z + bb.z);
      o.w = f2bf((v.w-mean)*r*gg.w + bb.w);
      *(bf16x4*)&xs[w*16 + it*2 + half][c4] = o;
    }
  }

  // ---- stage W^T (bf16) into wsd: wsd[n][k] = W[k][n] ----
  auto stageW = [&](const float* __restrict__ W) {
    #pragma unroll
    for (int it = 0; it < 16; ++it) {
      const int f = it*1024 + tid*4;
      const int k = f >> 7, n = f & 127;
      const float4 v = *(const float4*)&W[f];
      wsd[n  ][k] = f2bf(v.x);
      wsd[n+1][k] = f2bf(v.y);
      wsd[n+2][k] = f2bf(v.z);
      wsd[n+3][k] = f2bf(v.w);
    }
  };

  const int i = l & 15, q = l >> 4;
  auto gemm = [&](f32x4 (*acc)[2]) {
    #pragma unroll
    for (int kk = 0; kk < 4; ++kk) {
      bf16x8 a[4], bfr[2];
      #pragma unroll
      for (int mt = 0; mt < 4; ++mt) a[mt] = *(const bf16x8*)&xs[mt*16+i][kk*32+q*8];
      #pragma unroll
      for (int nt = 0; nt < 2; ++nt) bfr[nt] = *(const bf16x8*)&wsd[w*32+nt*16+i][kk*32+q*8];
      #pragma unroll
      for (int mt = 0; mt < 4; ++mt)
        #pragma unroll
        for (int nt = 0; nt < 2; ++nt)
          acc[mt][nt] = __builtin_amdgcn_mfma_f32_16x16x32_bf16(a[mt], bfr[nt], acc[mt][nt], 0, 0, 0);
    }
  };

  stageW(y == 0 ? Wq : (y == 1 ? Wk : Wv));
  __syncthreads();
  f32x4 acc[4][2];
  #pragma unroll
  for (int mt = 0; mt < 4; ++mt)
    #pragma unroll
    for (int nt = 0; nt < 2; ++nt) acc[mt][nt] = (f32x4){0.f,0.f,0.f,0.f};
  gemm(acc);

  if (y == 0) {
    #pragma unroll
    for (int mt = 0; mt < 4; ++mt)
      #pragma unroll
      for (int nt = 0; nt < 2; ++nt) {
        const int h = w*32 + nt*16 + i;
        #pragma unroll
        for (int r = 0; r < 4; ++r)
          Qp[(m0 + mt*16 + 4*q + r)*D_ + h] = f2bf(phi_(acc[mt][nt][r]));
      }
  } else if (y == 1) {
    #pragma unroll
    for (int mt = 0; mt < 4; ++mt)
      #pragma unroll
      for (int nt = 0; nt < 2; ++nt) {
        const int h = w*32 + nt*16 + i;
        const int t0 = m0 + mt*16 + 4*q;
        bf16x4 o;
        #pragma unroll
        for (int r = 0; r < 4; ++r) {
          const short bv = f2bf(phi_(acc[mt][nt][r]));
          Kp[(t0+r)*D_ + h] = bv;
          o[r] = bv;
        }
        *(bf16x4*)&KpT[h*NTOK + t0] = o;
      }
  } else {
    __syncthreads();                 // all waves done reading wsd (Wv)
    stageW(Wg);
    __syncthreads();
    f32x4 accg[4][2];
    #pragma unroll
    for (int mt = 0; mt < 4; ++mt)
      #pragma unroll
      for (int nt = 0; nt < 2; ++nt) accg[mt][nt] = (f32x4){0.f,0.f,0.f,0.f};
    gemm(accg);
    #pragma unroll
    for (int mt = 0; mt < 4; ++mt)
      #pragma unroll
      for (int nt = 0; nt < 2; ++nt) {
        const int h = w*32 + nt*16 + i;
        const int t0 = m0 + mt*16 + 4*q;
        const float bgd = bg[h];
        bf16x4 o;
        #pragma unroll
        for (int r = 0; r < 4; ++r) {
          const float gv = 1.f/(1.f + __expf(-(accg[mt][nt][r] + bgd)));
          o[r] = f2bf(acc[mt][nt][r] * gv);
        }
        *(bf16x4*)&VgT[h*NTOK + t0] = o;
      }
  }
}

// ============ K2: per-chunk KV^T[d][h] = sum_t Vg[t][d]*Kp[t][h] + Ksum ============
__global__ __launch_bounds__(256) void k_chunkkv(const short* __restrict__ KpT,
    const short* __restrict__ VgT,
    float* __restrict__ KVT, float* __restrict__ Ksum) {
  const int c = blockIdx.x, hh = blockIdx.y;
  const int tid = threadIdx.x;
  const int tb = c*CHUNK;
  __shared__ short vgl[128][72];
  __shared__ short kpl[64][72];
  __shared__ float ksp[64][5];
  #pragma unroll
  for (int u = tid; u < 1024; u += 256) {
    const int d = u >> 3, c8 = (u & 7)*8;
    *(bf16x8*)&vgl[d][c8] = *(const bf16x8*)&VgT[d*NTOK + tb + c8];
  }
  #pragma unroll
  for (int u = tid; u < 512; u += 256) {
    const int h = u >> 3, c8 = (u & 7)*8;
    *(bf16x8*)&kpl[h][c8] = *(const bf16x8*)&KpT[(hh*64+h)*NTOK + tb + c8];
  }
  __syncthreads();
  const int w = tid >> 6, l = tid & 63, i = l & 15, q = l >> 4;
  f32x4 acc[2][4];
  #pragma unroll
  for (int mt = 0; mt < 2; ++mt)
    #pragma unroll
    for (int nt = 0; nt < 4; ++nt) acc[mt][nt] = (f32x4){0.f,0.f,0.f,0.f};
  #pragma unroll
  for (int kk = 0; kk < 2; ++kk) {
    bf16x8 a[2], bb[4];
    #pragma unroll
    for (int mt = 0; mt < 2; ++mt) a[mt] = *(const bf16x8*)&vgl[(2*w+mt)*16+i][kk*32+q*8];
    #pragma unroll
    for (int nt = 0; nt < 4; ++nt) bb[nt] = *(const bf16x8*)&kpl[nt*16+i][kk*32+q*8];
    #pragma unroll
    for (int mt = 0; mt < 2; ++mt)
      #pragma unroll
      for (int nt = 0; nt < 4; ++nt)
        acc[mt][nt] = __builtin_amdgcn_mfma_f32_16x16x32_bf16(a[mt], bb[nt], acc[mt][nt], 0, 0, 0);
  }
  float* KVc = KVT + (size_t)c*16384;
  #pragma unroll
  for (int mt = 0; mt < 2; ++mt)
    #pragma unroll
    for (int nt = 0; nt < 4; ++nt)
      #pragma unroll
      for (int r = 0; r < 4; ++r) {
        const int d = (2*w+mt)*16 + 4*q + r;
        const int h = hh*64 + nt*16 + i;
        KVc[d*128 + h] = acc[mt][nt][r];
      }
  {
    const int h = tid >> 2, part = tid & 3;
    float s = 0.f;
    #pragma unroll
    for (int t = 0; t < 16; ++t) s += bf2f(kpl[h][part*16 + t]);
    ksp[h][part] = s;
  }
  __syncthreads();
  if (tid < 64)
    Ksum[c*128 + hh*64 + tid] = ksp[tid][0]+ksp[tid][1]+ksp[tid][2]+ksp[tid][3];
}

// ============ K3: prefix scan (blocks 0..128) || intra-chunk scores (129..256) ============
__global__ __launch_bounds__(256) void k_prescore(const float* __restrict__ KVT,
    short* __restrict__ KVTb, float* __restrict__ Ksum,
    const short* __restrict__ Qp, const short* __restrict__ Kp,
    short* __restrict__ A, float* __restrict__ rowsum) {
  const int tid = threadIdx.x;
  if (blockIdx.x < 128) {
    const int b = blockIdx.x >> 6;
    const int e = (blockIdx.x & 63)*256 + tid;
    const size_t base = (size_t)b*NCB*16384 + e;
    float run = 0.f;
    #pragma unroll 8
    for (int c = 0; c < NCB; ++c) {
      const float v = KVT[base + (size_t)c*16384];
      KVTb[base + (size_t)c*16384] = f2bf(run);
      run += v;
    }
    return;
  }
  if (blockIdx.x == 128) {
    const int b = tid >> 7, h = tid & 127;
    float run = 0.f;
    #pragma unroll 8
    for (int c = 0; c < NCB; ++c) {
      const int idx = (b*NCB + c)*128 + h;
      const float v = Ksum[idx];
      Ksum[idx] = run;
      run += v;
    }
    return;
  }
  // ---- scores for chunk c ----
  const int c = blockIdx.x - 129;
  const int tb = c*CHUNK;
  __shared__ short qpl[64][136], kpl[64][136];
  #pragma unroll
  for (int u = tid; u < 1024; u += 256) {
    const int t = u >> 4, c8 = (u & 15)*8;
    *(bf16x8*)&qpl[t][c8] = *(const bf16x8*)&Qp[(tb+t)*D_ + c8];
    *(bf16x8*)&kpl[t][c8] = *(const bf16x8*)&Kp[(tb+t)*D_ + c8];
  }
  __syncthreads();
  const int w = tid >> 6, l = tid & 63, i = l & 15, q = l >> 4;
  f32x4 acc[4];
  #pragma unroll
  for (int nt = 0; nt < 4; ++nt) acc[nt] = (f32x4){0.f,0.f,0.f,0.f};
  #pragma unroll
  for (int kk = 0; kk < 4; ++kk) {
    bf16x8 a = *(const bf16x8*)&qpl[w*16+i][kk*32+q*8];
    for (int nt = 0; nt <= w; ++nt) {
      bf16x8 bb = *(const bf16x8*)&kpl[nt*16+i][kk*32+q*8];
      acc[nt] = __builtin_amdgcn_mfma_f32_16x16x32_bf16(a, bb, acc[nt], 0, 0, 0);
    }
  }
  short* Ac = A + c*4096;
  float rs[4] = {0.f,0.f,0.f,0.f};
  #pragma unroll
  for (int nt = 0; nt < 4; ++nt) {
    #pragma unroll
    for (int r = 0; r < 4; ++r) {
      const int t = w*16 + 4*q + r;
      const int s = nt*16 + i;
      const float v = (nt <= w && s <= t) ? acc[nt][r] : 0.f;
      rs[r] += v;
      Ac[t*64 + s] = f2bf(v);
    }
  }
  #pragma unroll
  for (int r = 0; r < 4; ++r) {
    #pragma unroll
    for (int off = 1; off < 16; off <<= 1) rs[r] += __shfl_xor(rs[r], off);
  }
  if (i == 0) {
    #pragma unroll
    for (int r = 0; r < 4; ++r) rowsum[c*64 + w*16 + 4*q + r] = rs[r];
  }
}

// ============ K4: num = [A|Qp]@[Vg;S_prev], den = rowsum + Qp.Ksum, attn ============
__global__ __launch_bounds__(256) void k_attnout(const short* __restrict__ Aintra,
    const short* __restrict__ Qp, const short* __restrict__ VgT,
    const short* __restrict__ KVTb, const float* __restrict__ Ksum,
    const float* __restrict__ rowsum, short* __restrict__ attn) {
  const int c = blockIdx.x, dh = blockIdx.y, tid = threadIdx.x;
  const int tb = c*CHUNK;
  __shared__ short at[64][200], bt[64][200];
  __shared__ float ksl[128], dpart[64][4], denl[64];
  const short* Ac = Aintra + c*4096;
  #pragma unroll
  for (int u = tid; u < 512; u += 256) {
    const int t = u >> 3, c8 = (u & 7)*8;
    *(bf16x8*)&at[t][c8] = *(const bf16x8*)&Ac[t*64 + c8];
  }
  #pragma unroll
  for (int u = tid; u < 1024; u += 256) {
    const int t = u >> 4, c8 = (u & 15)*8;
    *(bf16x8*)&at[t][64 + c8] = *(const bf16x8*)&Qp[(tb+t)*D_ + c8];
  }
  #pragma unroll
  for (int u = tid; u < 512; u += 256) {
    const int dd = u >> 3, c8 = (u & 7)*8;
    *(bf16x8*)&bt[dd][c8] = *(const bf16x8*)&VgT[(dh*64+dd)*NTOK + tb + c8];
  }
  #pragma unroll
  for (int u = tid; u < 1024; u += 256) {
    const int dd = u >> 4, c8 = (u & 15)*8;
    *(bf16x8*)&bt[dd][64 + c8] = *(const bf16x8*)&KVTb[(size_t)c*16384 + (dh*64+dd)*128 + c8];
  }
  if (tid < 128) ksl[tid] = Ksum[c*128 + tid];
  __syncthreads();
  // denominator
  {
    const int t = tid >> 2, part = tid & 3;
    float dot = 0.f;
    #pragma unroll
    for (int h = 0; h < 32; ++h) dot += bf2f(at[t][64 + part*32 + h]) * ksl[part*32 + h];
    dpart[t][part] = dot;
  }
  __syncthreads();
  if (tid < 64)
    denl[tid] = fmaxf(rowsum[c*64 + tid] + dpart[tid][0]+dpart[tid][1]+dpart[tid][2]+dpart[tid][3], EPS_ATTN);
  __syncthreads();
  const int w = tid >> 6, l = tid & 63, i = l & 15, q = l >> 4;
  f32x4 acc[4];
  #pragma unroll
  for (int nt = 0; nt < 4; ++nt) acc[nt] = (f32x4){0.f,0.f,0.f,0.f};
  #pragma unroll
  for (int kk = 0; kk < 6; ++kk) {
    bf16x8 a = *(const bf16x8*)&at[w*16+i][kk*32+q*8];
    #pragma unroll
    for (int nt = 0; nt < 4; ++nt) {
      bf16x8 bb = *(const bf16x8*)&bt[nt*16+i][kk*32+q*8];
      acc[nt] = __builtin_amdgcn_mfma_f32_16x16x32_bf16(a, bb, acc[nt], 0, 0, 0);
    }
  }
  #pragma unroll
  for (int r = 0; r < 4; ++r) {
    const int t = w*16 + 4*q + r;
    const float inv = 1.f / denl[t];
    #pragma unroll
    for (int nt = 0; nt < 4; ++nt)
      attn[(size_t)(tb+t)*D_ + dh*64 + nt*16 + i] = f2bf(acc[nt][r] * inv);
  }
}

// ============ K5: out = LN2(tokens + 0.1*(attn@Wo)), Wo transposed in-block ============
__global__ __launch_bounds__(256) void k_outln2(const short* __restrict__ attn,
    const float* __restrict__ Wo, const float* __restrict__ tokens,
    const float* __restrict__ g2, const float* __restrict__ b2,
    float* __restrict__ out) {
  const int m0 = blockIdx.x*32, tid = threadIdx.x;
  __shared__ short al[32][136], wl[128][136];
  __shared__ float tl[32][132];
  __shared__ float suml[32][2], ssql[32][2];
  __shared__ float meanl[32], rstdl[32];
  __shared__ float gl[128], bl2[128];
  #pragma unroll
  for (int u = tid; u < 512; u += 256) {
    const int t = u >> 4, c8 = (u & 15)*8;
    *(bf16x8*)&al[t][c8] = *(const bf16x8*)&attn[(m0+t)*D_ + c8];
  }
  #pragma unroll
  for (int it = 0; it < 16; ++it) {
    const int f = it*1024 + tid*4;
    const int k = f >> 7, n = f & 127;
    const float4 v = *(const float4*)&Wo[f];
    wl[n  ][k] = f2bf(v.x);
    wl[n+1][k] = f2bf(v.y);
    wl[n+2][k] = f2bf(v.z);
    wl[n+3][k] = f2bf(v.w);
  }
  #pragma unroll
  for (int u = tid; u < 1024; u += 256) {
    const int t = u >> 5, c4 = (u & 31)*4;
    *(float4*)&tl[t][c4] = *(const float4*)&tokens[(m0+t)*D_ + c4];
  }
  if (tid < 128) { gl[tid] = g2[tid]; bl2[tid] = b2[tid]; }
  __syncthreads();
  const int w = tid >> 6, l = tid & 63, i = l & 15, q = l >> 4;
  const int mt = w >> 1, nh = w & 1;
  f32x4 acc[4];
  #pragma unroll
  for (int j = 0; j < 4; ++j) acc[j] = (f32x4){0.f,0.f,0.f,0.f};
  #pragma unroll
  for (int kk = 0; kk < 4; ++kk) {
    bf16x8 a = *(const bf16x8*)&al[mt*16+i][kk*32+q*8];
    #pragma unroll
    for (int j = 0; j < 4; ++j) {
      bf16x8 bb = *(const bf16x8*)&wl[(nh*4+j)*16+i][kk*32+q*8];
      acc[j] = __builtin_amdgcn_mfma_f32_16x16x32_bf16(a, bb, acc[j], 0, 0, 0);
    }
  }
  float p[4][4], ps[4], qs[4];
  #pragma unroll
  for (int r = 0; r < 4; ++r) {
    const int t = mt*16 + 4*q + r;
    ps[r] = 0.f; qs[r] = 0.f;
    #pragma unroll
    for (int j = 0; j < 4; ++j) {
      const int col = nh*64 + j*16 + i;
      const float v = tl[t][col] + 0.1f*acc[j][r];
      p[r][j] = v; ps[r] += v; qs[r] += v*v;
    }
  }
  #pragma unroll
  for (int r = 0; r < 4; ++r) {
    #pragma unroll
    for (int off = 1; off < 16; off <<= 1) {
      ps[r] += __shfl_xor(ps[r], off);
      qs[r] += __shfl_xor(qs[r], off);
    }
  }
  if (i == 0) {
    #pragma unroll
    for (int r = 0; r < 4; ++r) {
      suml[mt*16+4*q+r][nh] = ps[r];
      ssql[mt*16+4*q+r][nh] = qs[r];
    }
  }
  __syncthreads();
  if (tid < 32) {
    const float s = suml[tid][0] + suml[tid][1];
    const float qq = ssql[tid][0] + ssql[tid][1];
    const float mean = s*(1.f/D_);
    meanl[tid] = mean;
    rstdl[tid] = rsqrtf(qq*(1.f/D_) - mean*mean + LN_EPS);
  }
  __syncthreads();
  #pragma unroll
  for (int r = 0; r < 4; ++r) {
    const int t = mt*16 + 4*q + r;
    const float mean = meanl[t], rr = rstdl[t];
    #pragma unroll
    for (int j = 0; j < 4; ++j) {
      const int col = nh*64 + j*16 + i;
      out[(m0+t)*D_ + col] = (p[r][j]-mean)*rr*gl[col] + bl2[col];
    }
  }
}

extern "C" void kernel_launch(void* const* d_in, const int* in_sizes, int n_in,
                              void* d_out, int out_size, void* d_ws, size_t ws_size,
                              hipStream_t stream) {
  const float* tokens = (const float*)d_in[0];
  const float* Wq = (const float*)d_in[1];
  const float* Wk = (const float*)d_in[2];
  const float* Wv = (const float*)d_in[3];
  const float* Wg = (const float*)d_in[4];
  const float* bg = (const float*)d_in[5];
  const float* Wo = (const float*)d_in[6];
  const float* g1 = (const float*)d_in[7];
  const float* b1 = (const float*)d_in[8];
  const float* g2 = (const float*)d_in[9];
  const float* b2 = (const float*)d_in[10];

  char* base = (char*)d_ws;
  short* Qp     = (short*)(base);                        // 2MB
  short* Kp     = (short*)(base + (2u<<20));             // 2MB
  short* KpT    = (short*)(base + (4u<<20));             // 2MB
  short* VgT    = (short*)(base + (6u<<20));             // 2MB
  short* attn   = (short*)(base + (8u<<20));             // 2MB
  short* KVTb   = (short*)(base + (10u<<20));            // 4MB
  short* Aintra = (short*)(base + (14u<<20));            // 1MB
  float* rowsum = (float*)(base + (15u<<20));            // 32KB
  float* Ksum   = (float*)(base + (15u<<20) + (256u<<10)); // 64KB
  float* KVT    = (float*)(base + (16u<<20));            // 8MB

  k_qkvg<<<dim3(NTOK/64, 3), 256, 0, stream>>>(tokens, Wq, Wk, Wv, Wg, g1, b1, bg,
                                               Qp, Kp, KpT, VgT);
  k_chunkkv<<<dim3(NCH, 2), 256, 0, stream>>>(KpT, VgT, KVT, Ksum);
  k_prescore<<<257, 256, 0, stream>>>(KVT, KVTb, Ksum, Qp, Kp, Aintra, rowsum);
  k_attnout<<<dim3(NCH, 2), 256, 0, stream>>>(Aintra, Qp, VgT, KVTb, Ksum, rowsum, attn);
  k_outln2<<<NTOK/32, 256, 0, stream>>>(attn, Wo, tokens, g2, b2, (float*)d_out);
}